// Round 9
// baseline (288.850 us; speedup 1.0000x reference)
//
#include <hip/hip_runtime.h>

#define TT 4096
#define BLK 256
#define PER 16   // TT / BLK
#define EPSV 1e-8f

// XOR swizzle on a float index (R1-proven): spreads 64B-stride groups across
// banks while preserving 16B-group contiguity/alignment (bits 5-7 -> bits 2-4).
__device__ __forceinline__ int swzf(int a) {
  return a ^ (((a >> 5) & 7) << 2);
}

__global__ __launch_bounds__(BLK) void w2_loss_kernel(
    const float* __restrict__ traces,
    const float* __restrict__ q_raw,
    float* __restrict__ part) {
  __shared__ float ltr[TT];       // 16 KB trace redistribution buffer
  __shared__ float wave_sums[4];
  __shared__ float wave_red[4];

  const int tid = threadIdx.x;
  const int wv = tid >> 6;
  const int lane = tid & 63;
  const long trace = blockIdx.x;
  const float* __restrict__ tr = traces + trace * (long)TT;
  const float* __restrict__ qr = q_raw + trace * (long)TT;
  const int base = tid * PER;

  // ---- PACKED trace loads (ideal 16B/lane pattern): wave w covers its own
  // quarter; instr j spans 1KB contiguous. Then swizzled ds_write_b128. ----
  {
    const float4* tr4 = (const float4*)tr;
    float4 pk[4];
#pragma unroll
    for (int j = 0; j < 4; ++j) pk[j] = tr4[256 * wv + 64 * j + lane];
#pragma unroll
    for (int j = 0; j < 4; ++j) {
      const int A = (256 * wv + 64 * j + lane) * 4;   // float addr, 16B-aligned
      *(float4*)&ltr[swzf(A)] = pk[j];                // swz keeps 16B alignment
    }
  }
  __syncthreads();  // barrier A: trace fully in LDS (no other vmem outstanding)

  // ---- read own 16 contiguous floats back (swizzled, R1-proven pattern) ----
  const int swb = ((tid >> 1) & 7) << 2;  // == ((a>>5)&7)<<2 for a=16*tid+4j
  float4 trv[4];
#pragma unroll
  for (int j = 0; j < 4; ++j)
    trv[j] = *(const float4*)&ltr[(base + 4 * j) ^ swb];
  float nb = 0.0f;
  if (tid < BLK - 1) {
    const int a = base + PER;             // first float of thread tid+1
    nb = ltr[swzf(a)];
  }

  // s[i] = traces[i]^2 + eps for own 16 elements + right neighbor (as R0).
  float s[PER + 1];
#pragma unroll
  for (int j = 0; j < 4; ++j) {
    s[4 * j + 0] = trv[j].x * trv[j].x + EPSV;
    s[4 * j + 1] = trv[j].y * trv[j].y + EPSV;
    s[4 * j + 2] = trv[j].z * trv[j].z + EPSV;
    s[4 * j + 3] = trv[j].w * trv[j].w + EPSV;
  }
  s[PER] = (tid < BLK - 1) ? (nb * nb + EPSV) : 0.0f;

  // Per-thread cumtrapz prefix (rolling t; identical float ops as R0).
  float lc[PER + 1];
  lc[0] = 0.0f;
  {
    float t0 = (float)base * 1e-3f;
#pragma unroll
    for (int m = 0; m < PER; ++m) {
      float t1 = (float)(base + m + 1) * 1e-3f;
      float incr = 0.5f * (s[m] + s[m + 1]) * (t1 - t0);
      if (m == PER - 1) incr = (tid < BLK - 1) ? incr : 0.0f;
      lc[m + 1] = lc[m] + incr;
      t0 = t1;
    }
  }
  const float tot = lc[PER];

  // Wave-level inclusive scan of thread totals (wave = 64 lanes) — as R0.
  float v = tot;
#pragma unroll
  for (int off = 1; off < 64; off <<= 1) {
    float n = __shfl_up(v, off, 64);
    if (lane >= off) v += n;
  }
  if (lane == 63) wave_sums[wv] = v;
  __syncthreads();  // barrier B: wave_sums visible

  float wave_off = 0.0f;
  if (wv > 0) wave_off += wave_sums[0];
  if (wv > 1) wave_off += wave_sums[1];
  if (wv > 2) wave_off += wave_sums[2];
  const float excl = (v - tot) + wave_off;
  const float norm = wave_sums[0] + wave_sums[1] + wave_sums[2] + wave_sums[3];
  const float inv_norm = 1.0f / norm;

  // ---- Phase 2: cdf -> analytic-p interp -> loss. q is DEMAND-GATHERED from
  // global (no staging, no drain coupling); 16 loads batched per group of 8
  // for MLP (R7 structure). Per-thread addresses are ~16 consecutive floats
  // -> 1-2 cache lines, L1-captured. Arithmetic verbatim (bit-exact). ----
  float local = 0.0f;
  {
    float tlo = (tid == 0) ? 0.0f : (float)(base - 1) * 1e-3f;
    float tm = (float)base * 1e-3f;
#pragma unroll
    for (int g = 0; g < 2; ++g) {
      int idx[8];
      float ff[8];
#pragma unroll
      for (int mm = 0; mm < 8; ++mm) {
        const int m = 8 * g + mm;
        float x = (excl + lc[m]) * inv_norm;     // cdf in [0,1]
        float u = x * (float)(TT - 1);           // u >= 0 (all summands >= 0)
        int i0 = (int)u;                         // == floorf for u >= 0
        i0 = (i0 > TT - 2) ? TT - 2 : i0;
        float f = u - (float)i0;                 // >= 0 by construction
        idx[mm] = i0;
        ff[mm] = fminf(f, 1.0f);                 // jnp.interp endpoint clamp
      }
      float q0v[8], q1v[8];
#pragma unroll
      for (int mm = 0; mm < 8; ++mm) {
        q0v[mm] = qr[idx[mm]];                   // 16 independent global loads:
        q1v[mm] = qr[idx[mm] + 1];               // issue together, wait once
      }
#pragma unroll
      for (int mm = 0; mm < 8; ++mm) {
        const int m = 8 * g + mm;
        float thi = (float)(base + m + 1) * 1e-3f;
        float thi_w = thi;
        if (m == PER - 1) thi_w = (tid == BLK - 1) ? tm : thi;  // t[4095] edge
        float transport = q0v[mm] + ff[mm] * (q1v[mm] - q0v[mm]);
        float d = tm - transport;
        float w = 0.5f * (thi_w - tlo);          // collapsed trapz weight
        local += d * d * s[m] * w;               // ((d*d)*s[m])*w — as R0
        tlo = tm;
        tm = thi;
      }
    }
  }
  local *= inv_norm;

  // Block reduce, then ONE coalesced store per block — as R0.
#pragma unroll
  for (int off = 32; off > 0; off >>= 1) local += __shfl_down(local, off, 64);
  if (lane == 0) wave_red[wv] = local;
  __syncthreads();
  if (tid == 0) {
    part[blockIdx.x] = wave_red[0] + wave_red[1] + wave_red[2] + wave_red[3];
  }
}

__global__ __launch_bounds__(BLK) void reduce_kernel(
    const float* __restrict__ part, float* __restrict__ out, int n) {
  __shared__ float wave_red[4];
  const int tid = threadIdx.x;
  float local = 0.0f;
  for (int i = tid; i < n; i += BLK) local += part[i];
#pragma unroll
  for (int off = 32; off > 0; off >>= 1) local += __shfl_down(local, off, 64);
  if ((tid & 63) == 0) wave_red[tid >> 6] = local;
  __syncthreads();
  if (tid == 0) out[0] = wave_red[0] + wave_red[1] + wave_red[2] + wave_red[3];
}

extern "C" void kernel_launch(void* const* d_in, const int* in_sizes, int n_in,
                              void* d_out, int out_size, void* d_ws, size_t ws_size,
                              hipStream_t stream) {
  const float* traces = (const float*)d_in[0];
  const float* q_raw  = (const float*)d_in[3];
  float* out = (float*)d_out;
  float* part = (float*)d_ws;  // 8192 floats = 32 KB scratch

  const int n_traces = in_sizes[0] / TT;  // B*R = 8192
  w2_loss_kernel<<<n_traces, BLK, 0, stream>>>(traces, q_raw, part);
  reduce_kernel<<<1, BLK, 0, stream>>>(part, out, n_traces);
}